// Round 5
// baseline (377.365 us; speedup 1.0000x reference)
//
#include <hip/hip_runtime.h>
#include <cstdint>
#include <cstddef>

#define BATCH 64
#define NIN   1024
#define CIN   256
#define NC    32
#define NJC   16     // j-blocks per batch (64 j each)
#define JCH   64
#define T_EPS 1e-7f
#define CT_S  72     // cT row stride in u16 (144 B)
#define SCOPE_AGENT __HIP_MEMORY_SCOPE_AGENT

typedef __attribute__((ext_vector_type(8))) short short8;   // 8 bf16 = 4 VGPR
typedef __attribute__((ext_vector_type(4))) float floatx4;  // MFMA 16x16 acc

__device__ __forceinline__ unsigned short bf16rne(float f) {
  unsigned int u = __float_as_uint(f);
  u += 0x7FFFu + ((u >> 16) & 1u);
  return (unsigned short)(u >> 16);
}
__device__ __forceinline__ float bf2f(unsigned short h) {
  return __uint_as_float(((unsigned int)h) << 16);
}
// swizzled u16 index into the 64x256 LDS x-tile (16B chunks XOR-permuted per j)
__device__ __forceinline__ int xsw(int j, int c) {
  return j * 256 + ((((c >> 3) ^ (j & 7) ^ ((j >> 3) & 7)) << 3) | (c & 7));
}

// coherent (agent-scope) accessors — round-2-proven, bypass non-coherent L2
__device__ __forceinline__ float cload(const float* p) {
  return __hip_atomic_load(p, __ATOMIC_RELAXED, SCOPE_AGENT);
}
__device__ __forceinline__ void cstore(float* p, float v) {
  __hip_atomic_store(p, v, __ATOMIC_RELAXED, SCOPE_AGENT);
}
__device__ __forceinline__ unsigned int cloadu(const unsigned int* p) {
  return __hip_atomic_load(p, __ATOMIC_RELAXED, SCOPE_AGENT);
}
__device__ __forceinline__ void cstoreu(unsigned int* p, unsigned int v) {
  __hip_atomic_store(p, v, __ATOMIC_RELAXED, SCOPE_AGENT);
}

struct TPS { float ys2[8][CIN]; float os2[8][NC]; };   // 9 KB tail scratch
union USH { unsigned short cT[NC * CT_S]; };           // 4.5 KB softmax coeffs

// ---- K0: weight layouts for the fan-in tails ------------------------------
// Wq: s-dot layout. slice = (i>>3)*4 + ((i>>1)&3); within slice (32 KB):
//   u16 addr = (c>>3)*512 + ((i&1)*32 + k)*8 + (c&7)
//   -> a wave (64 lanes = (il2,k)) reads 1 KB contiguous per c8 step.
// Wp: wt-gen layout. short8 at ((i*4 + k8)*256 + c) = W[c][i*32+k8*8 .. +8]
//   -> lanes (c) read contiguous 16B each, perfectly coalesced.
__global__ __launch_bounds__(256) void k_wbuild(const float* __restrict__ W,
                                                unsigned short* __restrict__ Wq,
                                                unsigned short* __restrict__ Wp) {
  const int i = blockIdx.x, t = threadIdx.x;   // t = c
  const float4* wsrc = (const float4*)(W + (size_t)t * 1024 + i * 32);
  const int slice = (i >> 3) * 4 + ((i >> 1) & 3);
  const int il2 = i & 1;
  unsigned short* qb = Wq + (size_t)slice * 16384 + (t >> 3) * 512 + (t & 7);
  #pragma unroll
  for (int k8 = 0; k8 < 4; ++k8) {
    float4 v0 = wsrc[k8 * 2], v1 = wsrc[k8 * 2 + 1];
    unsigned short h[8] = {bf16rne(v0.x), bf16rne(v0.y), bf16rne(v0.z), bf16rne(v0.w),
                           bf16rne(v1.x), bf16rne(v1.y), bf16rne(v1.z), bf16rne(v1.w)};
    short8 pv;
    #pragma unroll
    for (int e = 0; e < 8; ++e) {
      int k = k8 * 8 + e;
      qb[(il2 * 32 + k) * 8] = h[e];
      pv[e] = (short)h[e];
    }
    *(short8*)&Wp[(((size_t)i * 4 + k8) * CIN + t) * 8] = pv;
  }
}

// ---- fan-in tail: reduce -> squash -> wt (or final out) for ALL 32 i of b -
// MODE 0: ys common from y0p fp32 (/32). MODE 1: ys from yp32 bf16-pairs,
// write wt. MODE 2: write final out.
template <int MODE>
__device__ __forceinline__ void tail_post(int b, int t,
    const float* __restrict__ y0p, const unsigned int* __restrict__ yp32,
    const unsigned short* __restrict__ Wq, const unsigned short* __restrict__ Wp,
    unsigned short* __restrict__ wtb, float* __restrict__ outg, TPS* tp) {
  const int w = t >> 6, lane = t & 63, il = t >> 5, k = t & 31;
  if (MODE == 0) {
    float a = 0.f;
    #pragma unroll
    for (int p = 0; p < NJC; ++p) a += cload(&y0p[(b * NJC + p) * CIN + t]);
    tp->ys2[0][t] = a * (1.f / 32.f);
  }
  #pragma unroll 1
  for (int g4 = 0; g4 < 4; ++g4) {
    if (MODE != 0) {
      // ys2[l][c=t] = sum_p ypart[b][p][g4*8+l][c]  (bf16-pair agent loads)
      #pragma unroll 1
      for (int l = 0; l < 8; ++l) {
        float a = 0.f;
        #pragma unroll
        for (int p = 0; p < NJC; ++p) {
          unsigned int v =
              cloadu(&yp32[(((size_t)(b * NJC + p)) * NC + g4 * 8 + l) * 128 + (t >> 1)]);
          a += bf2f((unsigned short)((t & 1) ? (v >> 16) : (v & 0xffffu)));
        }
        tp->ys2[l][t] = a;
      }
    }
    __syncthreads();
    {
      // s-dot: thread (il,k), i = g4*8+il ; coalesced Wq slice reads
      const float* ysrow = (MODE == 0) ? tp->ys2[0] : tp->ys2[il];
      const short8* wq = (const short8*)Wq + ((size_t)(g4 * 4 + w)) * 2048 + lane;
      float s = 0.f;
      #pragma unroll 8
      for (int c8 = 0; c8 < 32; ++c8) {
        short8 wv = wq[c8 * 64];
        #pragma unroll
        for (int e = 0; e < 8; ++e) s += ysrow[c8 * 8 + e] * bf2f((unsigned short)wv[e]);
      }
      float s2 = s * s;
      #pragma unroll
      for (int m = 1; m < 32; m <<= 1) s2 += __shfl_xor(s2, m);
      float o = s * rsqrtf(s2 + T_EPS);
      if (MODE == 2) outg[((size_t)b * NC + g4 * 8 + il) * 32 + k] = o;
      else tp->os2[il][k] = o;
    }
    __syncthreads();
    if (MODE != 2) {
      // wt-gen: thread = c ; coalesced Wp reads
      #pragma unroll 1
      for (int l = 0; l < 8; ++l) {
        int i = g4 * 8 + l;
        float acc = 0.f;
        #pragma unroll
        for (int k8 = 0; k8 < 4; ++k8) {
          short8 wv = *((const short8*)Wp + ((size_t)i * 4 + k8) * CIN + t);
          #pragma unroll
          for (int e = 0; e < 8; ++e)
            acc += tp->os2[l][k8 * 8 + e] * bf2f((unsigned short)wv[e]);
        }
        wtb[((size_t)b * NC + i) * CIN + t] = bf16rne(acc);
      }
      __syncthreads();   // os2/ys2 reused next g4
    }
  }
}

// ---- K_A: x fp32 -> xb bf16 + colsum partials + fan-in post0 --------------
__global__ __launch_bounds__(256) void k_convA(const float* __restrict__ x,
    unsigned short* __restrict__ xb, float* __restrict__ y0p,
    const unsigned short* __restrict__ Wq, const unsigned short* __restrict__ Wp,
    unsigned short* __restrict__ wtb, unsigned int* __restrict__ dc) {
  const int jc = blockIdx.x, b = blockIdx.y, t = threadIdx.x;
  const int jj = t >> 6, c4 = t & 63;
  union ALDS { float4 red[4][64]; TPS tp; };
  __shared__ ALDS s_;
  __shared__ int lastf;
  const float4* xg = (const float4*)(x + ((size_t)(b * NIN + jc * JCH)) * CIN);
  ushort4* xo = (ushort4*)(xb + ((size_t)(b * NIN + jc * JCH)) * CIN);
  float4 acc = make_float4(0.f, 0.f, 0.f, 0.f);
  #pragma unroll
  for (int jr = 0; jr < 16; ++jr) {
    int j = jr * 4 + jj;
    float4 v = xg[j * 64 + c4];
    acc.x += v.x; acc.y += v.y; acc.z += v.z; acc.w += v.w;
    ushort4 h;
    h.x = bf16rne(v.x); h.y = bf16rne(v.y);
    h.z = bf16rne(v.z); h.w = bf16rne(v.w);
    xo[j * 64 + c4] = h;
  }
  s_.red[jj][c4] = acc;
  __syncthreads();
  if (t < 64) {
    float4 s = s_.red[0][t];
    #pragma unroll
    for (int p = 1; p < 4; ++p) {
      s.x += s_.red[p][t].x; s.y += s_.red[p][t].y;
      s.z += s_.red[p][t].z; s.w += s_.red[p][t].w;
    }
    float* dst = y0p + ((size_t)(b * NJC + jc)) * CIN + t * 4;
    cstore(dst + 0, s.x); cstore(dst + 1, s.y);
    cstore(dst + 2, s.z); cstore(dst + 3, s.w);
  }
  __syncthreads();   // drains the agent stores (vmcnt) before the fan-in add
  if (t == 0)
    lastf = (__hip_atomic_fetch_add(&dc[b], 1u, __ATOMIC_ACQ_REL, SCOPE_AGENT) == NJC - 1);
  __syncthreads();
  if (!lastf) return;
  tail_post<0>(b, t, y0p, nullptr, Wq, Wp, wtb, nullptr, &s_.tp);
}

// ---- K_B/K_C: fused routing iter + fan-in post ----------------------------
// FM==1: tail writes wt (in-place safe: all A-phase reads of wt[b] precede
// the fan-in). FM==2: tail writes final out.
template <int FM>
__global__ __launch_bounds__(256, 4) void k_fusedm(const unsigned short* __restrict__ xb,
    const unsigned short* __restrict__ wt, unsigned int* __restrict__ yp32,
    const unsigned short* __restrict__ Wq, const unsigned short* __restrict__ Wp,
    unsigned short* __restrict__ wtout, float* __restrict__ outg,
    unsigned int* __restrict__ dc) {
  const int jc = blockIdx.x, b = blockIdx.y, t = threadIdx.x;
  const int w = t >> 6, l16 = t & 15, q = (t >> 4) & 3;
  union FLDS { unsigned short xs[64 * 256]; TPS tp; };
  __shared__ FLDS sm;   // 32 KB x-tile, aliased by tail scratch afterwards
  __shared__ USH u;
  __shared__ int lastf;
  {
    const short8* xg = (const short8*)(xb + ((size_t)(b * NIN) + (size_t)jc * JCH) * CIN);
    #pragma unroll
    for (int it = 0; it < 8; ++it) {
      int fi = it * 256 + t;
      int j = fi >> 5, ch = fi & 31;
      *(short8*)&sm.xs[xsw(j, ch * 8)] = xg[fi];
    }
  }
  const int jloc = w * 16 + l16;
  const unsigned short* wrow = wt + (size_t)b * NC * CIN;
  floatx4 accA0 = {0.f, 0.f, 0.f, 0.f}, accA1 = {0.f, 0.f, 0.f, 0.f};
  __syncthreads();
  #pragma unroll
  for (int ks = 0; ks < 8; ++ks) {
    short8 bx = *(const short8*)&sm.xs[xsw(jloc, ks * 32 + q * 8)];
    short8 a0 = *(const short8*)(wrow + (size_t)l16 * CIN + ks * 32 + q * 8);
    short8 a1 = *(const short8*)(wrow + (size_t)(16 + l16) * CIN + ks * 32 + q * 8);
    accA0 = __builtin_amdgcn_mfma_f32_16x16x32_bf16(a0, bx, accA0, 0, 0, 0);
    accA1 = __builtin_amdgcn_mfma_f32_16x16x32_bf16(a1, bx, accA1, 0, 0, 0);
  }
  {
    float m = accA0[0];
    #pragma unroll
    for (int r = 1; r < 4; ++r) m = fmaxf(m, accA0[r]);
    #pragma unroll
    for (int r = 0; r < 4; ++r) m = fmaxf(m, accA1[r]);
    m = fmaxf(m, __shfl_xor(m, 16));
    m = fmaxf(m, __shfl_xor(m, 32));
    float e0[4], e1[4], s = 0.f;
    #pragma unroll
    for (int r = 0; r < 4; ++r) {
      e0[r] = __expf(accA0[r] - m);
      e1[r] = __expf(accA1[r] - m);
      s += e0[r] + e1[r];
    }
    s += __shfl_xor(s, 16);
    s += __shfl_xor(s, 32);
    float rs = 1.f / s;
    #pragma unroll
    for (int r = 0; r < 4; ++r) {
      u.cT[(q * 4 + r) * CT_S + jloc]      = bf16rne(e0[r] * rs);
      u.cT[(16 + q * 4 + r) * CT_S + jloc] = bf16rne(e1[r] * rs);
    }
  }
  __syncthreads();
  const int cw = w * 64;
  floatx4 accB[2][4];
  #pragma unroll
  for (int h = 0; h < 2; ++h)
    #pragma unroll
    for (int ct = 0; ct < 4; ++ct) accB[h][ct] = (floatx4){0.f, 0.f, 0.f, 0.f};
  #pragma unroll
  for (int ks = 0; ks < 2; ++ks) {
    short8 ca0 = *(const short8*)&u.cT[l16 * CT_S + ks * 32 + q * 8];
    short8 ca1 = *(const short8*)&u.cT[(16 + l16) * CT_S + ks * 32 + q * 8];
    #pragma unroll
    for (int ct = 0; ct < 4; ++ct) {
      const int c = cw + ct * 16 + l16;
      short8 xf;
      #pragma unroll
      for (int e = 0; e < 8; ++e)
        xf[e] = (short)sm.xs[xsw(ks * 32 + q * 8 + e, c)];
      accB[0][ct] = __builtin_amdgcn_mfma_f32_16x16x32_bf16(ca0, xf, accB[0][ct], 0, 0, 0);
      accB[1][ct] = __builtin_amdgcn_mfma_f32_16x16x32_bf16(ca1, xf, accB[1][ct], 0, 0, 0);
    }
  }
  // partial y store: pack bf16 pairs via lane exchange, agent-scope u32
  #pragma unroll
  for (int h = 0; h < 2; ++h)
    #pragma unroll
    for (int ct = 0; ct < 4; ++ct)
      #pragma unroll
      for (int r = 0; r < 4; ++r) {
        float fv = accB[h][ct][r];
        float gv = __shfl_xor(fv, 1);
        if ((l16 & 1) == 0) {
          int i = h * 16 + q * 4 + r;
          int c = cw + ct * 16 + l16;
          cstoreu(&yp32[(((size_t)(b * NJC + jc)) * NC + i) * 128 + (c >> 1)],
                  (unsigned int)bf16rne(fv) | ((unsigned int)bf16rne(gv) << 16));
        }
      }
  __syncthreads();   // drains the agent stores before the fan-in add
  if (t == 0)
    lastf = (__hip_atomic_fetch_add(&dc[b], 1u, __ATOMIC_ACQ_REL, SCOPE_AGENT) == NJC - 1);
  __syncthreads();
  if (!lastf) return;
  tail_post<FM>(b, t, nullptr, yp32, Wq, Wp, wtout, outg, &sm.tp);
}

// ===========================================================================

extern "C" void kernel_launch(void* const* d_in, const int* in_sizes, int n_in,
                              void* d_out, int out_size, void* d_ws, size_t ws_size,
                              hipStream_t stream) {
  (void)in_sizes; (void)n_in; (void)out_size; (void)ws_size;
  const float* x = (const float*)d_in[0];
  const float* W = (const float*)d_in[1];
  float* out = (float*)d_out;
  char* ws = (char*)d_ws;
  // ws: xb 32M @0 | wt 1M @32M | yp32 16.8M @33M | y0p 1M @50M |
  //     Wq 512K @51M | Wp 512K @51.5M | dcnt 768B @52M
  unsigned short* xb   = (unsigned short*)ws;
  unsigned short* wtb  = (unsigned short*)(ws + (32ull << 20));
  unsigned int*   yp32 = (unsigned int*)(ws + (33ull << 20));
  float*          y0p  = (float*)(ws + (50ull << 20));
  unsigned short* Wq   = (unsigned short*)(ws + (51ull << 20));
  unsigned short* Wp   = (unsigned short*)(ws + (51ull << 20) + (512ull << 10));
  unsigned int*   dcnt = (unsigned int*)(ws + (52ull << 20));

  (void)hipMemsetAsync(dcnt, 0, 3 * BATCH * sizeof(unsigned int), stream);

  dim3 g(NJC, BATCH);   // (16, 64)
  k_wbuild<<<dim3(NC), 256, 0, stream>>>(W, Wq, Wp);
  k_convA<<<g, 256, 0, stream>>>(x, xb, y0p, Wq, Wp, wtb, dcnt);
  k_fusedm<1><<<g, 256, 0, stream>>>(xb, wtb, yp32, Wq, Wp, wtb, nullptr, dcnt + BATCH);
  k_fusedm<2><<<g, 256, 0, stream>>>(xb, wtb, yp32, Wq, Wp, nullptr, out, dcnt + 2 * BATCH);
}

// Round 6
// 163.921 us; speedup vs baseline: 2.3021x; 2.3021x over previous
//
#include <hip/hip_runtime.h>
#include <cstdint>
#include <cstddef>

#define BATCH 64
#define NIN   1024
#define CIN   256
#define NC    32
#define NJC   16     // j-blocks per batch (64 j each)
#define JCH   64
#define T_EPS 1e-7f
#define CT_S  72     // cT row stride in u16 (144 B)

typedef __attribute__((ext_vector_type(8))) short short8;   // 8 bf16 = 4 VGPR
typedef __attribute__((ext_vector_type(4))) float floatx4;  // MFMA 16x16 acc

__device__ __forceinline__ unsigned short bf16rne(float f) {
  unsigned int u = __float_as_uint(f);
  u += 0x7FFFu + ((u >> 16) & 1u);
  return (unsigned short)(u >> 16);
}
__device__ __forceinline__ float bf2f(unsigned short h) {
  return __uint_as_float(((unsigned int)h) << 16);
}
// swizzled u16 index into the transposed 256x64 LDS x-tile.
// swz uses c bits 0..2 XOR 3..5: spreads banks for BOTH the staging writes
// (c = ks*32+q*8+e varies in bits 3..4 per inst) and the phase-B reads
// (c = cw+ct*16+l16 varies in bits 0..3 per 16-lane group). XOR value is a
// multiple of 8 -> 8-elem chunks stay contiguous -> b128 reads stay legal.
__device__ __forceinline__ int xtsw(int c, int j) {
  return c * 64 + (j ^ ((((c) ^ ((c) >> 3)) & 7) << 3));
}

union USH {
  unsigned short cT[NC * CT_S]; // 4.5 KB (fused softmax coeffs)
};

// ---- K1: colsum partials + Wi/WiT build (b==0) ----------------------------
// grid (jc=16, b=64). x read warms L3 for the two k_fusedr passes.
// Wi[i][c][k] (for wt-gen b128 reads) ; WiT[i][k][c] (for s-dot b128 reads).
__global__ __launch_bounds__(256) void k_colsum(const float* __restrict__ x,
                                                const float* __restrict__ W,
                                                unsigned short* __restrict__ Wi,
                                                unsigned short* __restrict__ WiT,
                                                float* __restrict__ y0p) {
  const int jc = blockIdx.x, b = blockIdx.y, t = threadIdx.x;
  const int jj = t >> 6, c4 = t & 63;
  __shared__ float4 red[4][64];
  const float4* xg = (const float4*)(x + ((size_t)(b * NIN + jc * JCH)) * CIN);
  float4 acc = make_float4(0.f, 0.f, 0.f, 0.f);
  #pragma unroll
  for (int jr = 0; jr < 16; ++jr) {
    int j = jr * 4 + jj;
    float4 v = xg[j * 64 + c4];
    acc.x += v.x; acc.y += v.y; acc.z += v.z; acc.w += v.w;
  }
  red[jj][c4] = acc;
  if (b == 0) {
    // build Wi/WiT rows for i = jc*2, jc*2+1 ; thread t <-> c
    #pragma unroll
    for (int i2 = 0; i2 < 2; ++i2) {
      int i = jc * 2 + i2;
      const float4* wsrc = (const float4*)(W + (size_t)t * 1024 + i * 32);
      unsigned short* wdst = Wi + ((size_t)i * CIN + t) * NC;
      unsigned short* wtd  = WiT + (size_t)i * 32 * CIN + t;
      #pragma unroll
      for (int k4 = 0; k4 < 8; ++k4) {
        float4 v = wsrc[k4];
        ushort4 h;
        h.x = bf16rne(v.x); h.y = bf16rne(v.y);
        h.z = bf16rne(v.z); h.w = bf16rne(v.w);
        *(ushort4*)&wdst[k4 * 4] = h;
        wtd[(size_t)(k4 * 4 + 0) * CIN] = h.x;
        wtd[(size_t)(k4 * 4 + 1) * CIN] = h.y;
        wtd[(size_t)(k4 * 4 + 2) * CIN] = h.z;
        wtd[(size_t)(k4 * 4 + 3) * CIN] = h.w;
      }
    }
  }
  __syncthreads();
  if (t < 64) {
    float4 s = red[0][t];
    #pragma unroll
    for (int p = 1; p < 4; ++p) {
      s.x += red[p][t].x; s.y += red[p][t].y;
      s.z += red[p][t].z; s.w += red[p][t].w;
    }
    *(float4*)&y0p[(b * NJC + jc) * CIN + t * 4] = s;
  }
}

// ---- K2: y-reduce -> s = y@W_i -> squash -> wt(bf16) or out ---------------
// grid (i=NC, b=BATCH). MODE 0: yin=y0p fp32 (scale 1/32). MODE 1: yin=ypart
// bf16 [b][jc][i][c], write wt. MODE 2: write out.
template <int MODE>
__global__ __launch_bounds__(256) void k_post(const void* __restrict__ yin,
                                              const unsigned short* __restrict__ Wi,
                                              const unsigned short* __restrict__ WiT,
                                              unsigned short* __restrict__ wtout,
                                              float* __restrict__ outg) {
  const int i = blockIdx.x, b = blockIdx.y, t = threadIdx.x;
  const int k = t & 31, g = t >> 5;
  __shared__ float ys[CIN];
  __shared__ float sred[8][32];
  __shared__ float os[NC];
  // early-issue: WiT chunk for s-dot (this thread's (k, c-quarter))
  short8 wv[4];
  {
    const short8* wtrow = (const short8*)(WiT + ((size_t)i * 32 + k) * CIN + g * 32);
    #pragma unroll
    for (int m = 0; m < 4; ++m) wv[m] = wtrow[m];
  }
  // early-issue: Wi row for wt-gen (only needed when producing wt)
  short8 wr[4];
  if constexpr (MODE != 2) {
    const short8* wrow = (const short8*)(Wi + ((size_t)i * CIN + t) * NC);
    #pragma unroll
    for (int m = 0; m < 4; ++m) wr[m] = wrow[m];
  }
  // step 1: reduce partial y for (b,i); lane t <-> c
  float a = 0.f;
  if (MODE == 0) {
    const float* y0p = (const float*)yin;
    #pragma unroll
    for (int p = 0; p < NJC; ++p) a += y0p[(b * NJC + p) * CIN + t];
    a *= (1.f / 32.f);
  } else {
    const unsigned short* yp = (const unsigned short*)yin;
    #pragma unroll
    for (int p = 0; p < NJC; ++p)
      a += bf2f(yp[(((size_t)(b * NJC + p)) * NC + i) * CIN + t]);
  }
  ys[t] = a;
  __syncthreads();
  // step 2: s[k] partials over this thread's c-quarter (broadcast ys reads)
  {
    float ps = 0.f;
    #pragma unroll
    for (int m = 0; m < 4; ++m)
      #pragma unroll
      for (int e = 0; e < 8; ++e)
        ps += ys[g * 32 + m * 8 + e] * bf2f((unsigned short)wv[m][e]);
    sred[g][k] = ps;
  }
  __syncthreads();
  float s = 0.f;
  #pragma unroll
  for (int g8 = 0; g8 < 8; ++g8) s += sred[g8][k];
  float s2 = s * s;
  #pragma unroll
  for (int m = 1; m < 32; m <<= 1) s2 += __shfl_xor(s2, m);
  float o = s * rsqrtf(s2 + T_EPS);
  if constexpr (MODE == 2) {
    if (t < 32) outg[((size_t)b * NC + i) * 32 + t] = o;
  } else {
    if (t < 32) os[t] = o;
    __syncthreads();
    float acc = 0.f;
    #pragma unroll
    for (int k8 = 0; k8 < 4; ++k8) {
      #pragma unroll
      for (int e = 0; e < 8; ++e)
        acc += os[k8 * 8 + e] * bf2f((unsigned short)wr[k8][e]);
    }
    wtout[((size_t)b * NC + i) * CIN + t] = bf16rne(acc);
  }
}

// ---- K3/K5: fused routing iteration, register A-operand + transposed LDS --
// Phase A (L = wt@x^T): x fragments live in registers (loaded straight from
// L3-hot fp32 x, converted once). The same registers are scattered into the
// transposed, swizzled xT tile, which phase B (y = c@x) reads with aligned
// b128 loads — no column gather, no bank conflicts. One barrier total.
__global__ __launch_bounds__(256, 4) void k_fusedr(const float* __restrict__ x,
                                                   const unsigned short* __restrict__ wt,
                                                   unsigned short* __restrict__ ypart) {
  const int jc = blockIdx.x, b = blockIdx.y, t = threadIdx.x;
  const int w = t >> 6, l16 = t & 15, q = (t >> 4) & 3;
  const int jloc = w * 16 + l16;
  __shared__ __align__(16) unsigned short xT[CIN * JCH];  // 32 KB transposed
  __shared__ USH u;
  const unsigned short* wrow = wt + (size_t)b * NC * CIN;
  // wt a-fragments for ks=0,1 prefetched (L2-hot, hide under x loads)
  short8 a0p0 = *(const short8*)(wrow + (size_t)l16 * CIN + 0 * 32 + q * 8);
  short8 a1p0 = *(const short8*)(wrow + (size_t)(16 + l16) * CIN + 0 * 32 + q * 8);
  short8 a0p1 = *(const short8*)(wrow + (size_t)l16 * CIN + 1 * 32 + q * 8);
  short8 a1p1 = *(const short8*)(wrow + (size_t)(16 + l16) * CIN + 1 * 32 + q * 8);
  // x loads: row jloc, c = ks*32 + q*8 .. +8 for ks=0..7 (exactly the 64
  // elements this thread's A-fragments need). Per inst: 16 rows x 128B.
  const float4* xg = (const float4*)(x + ((size_t)(b * NIN + jc * JCH) + jloc) * CIN);
  float4 xv[16];
  #pragma unroll
  for (int ks = 0; ks < 8; ++ks) {
    xv[ks * 2]     = xg[ks * 8 + q * 2];
    xv[ks * 2 + 1] = xg[ks * 8 + q * 2 + 1];
  }
  // convert once; keep bf16 fragments for phase A; scatter into xT for B.
  short8 bxf[8];
  #pragma unroll
  for (int ks = 0; ks < 8; ++ks) {
    float f[8] = {xv[ks * 2].x,     xv[ks * 2].y,     xv[ks * 2].z,     xv[ks * 2].w,
                  xv[ks * 2 + 1].x, xv[ks * 2 + 1].y, xv[ks * 2 + 1].z, xv[ks * 2 + 1].w};
    short8 h8;
    #pragma unroll
    for (int e = 0; e < 8; ++e) h8[e] = (short)bf16rne(f[e]);
    bxf[ks] = h8;
    #pragma unroll
    for (int e = 0; e < 8; ++e) {
      int c = ks * 32 + q * 8 + e;
      xT[xtsw(c, jloc)] = (unsigned short)h8[e];
    }
  }
  // ---- phase A: L[i][j] = sum_c wt[i][c] x[j][c]  (no LDS reads) ----------
  floatx4 accA0 = {0.f, 0.f, 0.f, 0.f}, accA1 = {0.f, 0.f, 0.f, 0.f};
  accA0 = __builtin_amdgcn_mfma_f32_16x16x32_bf16(a0p0, bxf[0], accA0, 0, 0, 0);
  accA1 = __builtin_amdgcn_mfma_f32_16x16x32_bf16(a1p0, bxf[0], accA1, 0, 0, 0);
  accA0 = __builtin_amdgcn_mfma_f32_16x16x32_bf16(a0p1, bxf[1], accA0, 0, 0, 0);
  accA1 = __builtin_amdgcn_mfma_f32_16x16x32_bf16(a1p1, bxf[1], accA1, 0, 0, 0);
  #pragma unroll
  for (int ks = 2; ks < 8; ++ks) {
    short8 a0 = *(const short8*)(wrow + (size_t)l16 * CIN + ks * 32 + q * 8);
    short8 a1 = *(const short8*)(wrow + (size_t)(16 + l16) * CIN + ks * 32 + q * 8);
    accA0 = __builtin_amdgcn_mfma_f32_16x16x32_bf16(a0, bxf[ks], accA0, 0, 0, 0);
    accA1 = __builtin_amdgcn_mfma_f32_16x16x32_bf16(a1, bxf[ks], accA1, 0, 0, 0);
  }
  // ---- softmax over i (column j held per lane-pair group) -----------------
  {
    float m = accA0[0];
    #pragma unroll
    for (int r = 1; r < 4; ++r) m = fmaxf(m, accA0[r]);
    #pragma unroll
    for (int r = 0; r < 4; ++r) m = fmaxf(m, accA1[r]);
    m = fmaxf(m, __shfl_xor(m, 16));
    m = fmaxf(m, __shfl_xor(m, 32));
    float e0[4], e1[4], s = 0.f;
    #pragma unroll
    for (int r = 0; r < 4; ++r) {
      e0[r] = __expf(accA0[r] - m);
      e1[r] = __expf(accA1[r] - m);
      s += e0[r] + e1[r];
    }
    s += __shfl_xor(s, 16);
    s += __shfl_xor(s, 32);
    float rs = 1.f / s;
    #pragma unroll
    for (int r = 0; r < 4; ++r) {
      u.cT[(q * 4 + r) * CT_S + jloc]      = bf16rne(e0[r] * rs);
      u.cT[(16 + q * 4 + r) * CT_S + jloc] = bf16rne(e1[r] * rs);
    }
  }
  __syncthreads();   // xT writes + cT writes -> visible for phase B
  // ---- phase B: y[i][c] = sum_j c[i][j] x[j][c]  (b128 xT reads) ----------
  const int cw = w * 64;
  floatx4 accB[2][4];
  #pragma unroll
  for (int h = 0; h < 2; ++h)
    #pragma unroll
    for (int ct = 0; ct < 4; ++ct) accB[h][ct] = (floatx4){0.f, 0.f, 0.f, 0.f};
  #pragma unroll
  for (int ks = 0; ks < 2; ++ks) {
    short8 ca0 = *(const short8*)&u.cT[l16 * CT_S + ks * 32 + q * 8];
    short8 ca1 = *(const short8*)&u.cT[(16 + l16) * CT_S + ks * 32 + q * 8];
    #pragma unroll
    for (int ct = 0; ct < 4; ++ct) {
      const int c = cw + ct * 16 + l16;
      short8 xf = *(const short8*)&xT[xtsw(c, ks * 32 + q * 8)];
      accB[0][ct] = __builtin_amdgcn_mfma_f32_16x16x32_bf16(ca0, xf, accB[0][ct], 0, 0, 0);
      accB[1][ct] = __builtin_amdgcn_mfma_f32_16x16x32_bf16(ca1, xf, accB[1][ct], 0, 0, 0);
    }
  }
  unsigned short* yo = ypart + ((size_t)(b * NJC + jc)) * NC * CIN;
  #pragma unroll
  for (int h = 0; h < 2; ++h)
    #pragma unroll
    for (int ct = 0; ct < 4; ++ct)
      #pragma unroll
      for (int r = 0; r < 4; ++r) {
        int i = h * 16 + q * 4 + r;
        int c = cw + ct * 16 + l16;
        yo[i * CIN + c] = bf16rne(accB[h][ct][r]);
      }
}

// ===========================================================================

extern "C" void kernel_launch(void* const* d_in, const int* in_sizes, int n_in,
                              void* d_out, int out_size, void* d_ws, size_t ws_size,
                              hipStream_t stream) {
  (void)in_sizes; (void)n_in; (void)out_size; (void)ws_size;
  const float* x = (const float*)d_in[0];
  const float* W = (const float*)d_in[1];
  float* out = (float*)d_out;
  char* ws = (char*)d_ws;
  // ws: wt 1MiB @0 | ypart 16MiB @1M | y0p 1MiB @17M | Wi 512K @18M | WiT 512K @18.5M
  unsigned short* wtb   = (unsigned short*)ws;
  unsigned short* ypart = (unsigned short*)(ws + (1ull << 20));
  float*          y0p   = (float*)(ws + (17ull << 20));
  unsigned short* Wi    = (unsigned short*)(ws + (18ull << 20));
  unsigned short* WiT   = (unsigned short*)(ws + (18ull << 20) + (512ull << 10));

  dim3 gfuse(NJC, BATCH);     // (16, 64)
  dim3 gpost(NC, BATCH);      // (32, 64)
  k_colsum<<<gfuse, 256, 0, stream>>>(x, W, Wi, WiT, y0p);
  k_post<0><<<gpost, 256, 0, stream>>>(y0p, Wi, WiT, wtb, nullptr);    // iter 0
  k_fusedr<<<gfuse, 256, 0, stream>>>(x, wtb, ypart);                  // iter 1
  k_post<1><<<gpost, 256, 0, stream>>>(ypart, Wi, WiT, wtb, nullptr);
  k_fusedr<<<gfuse, 256, 0, stream>>>(x, wtb, ypart);                  // iter 2
  k_post<2><<<gpost, 256, 0, stream>>>(ypart, Wi, WiT, nullptr, out);
}